// Round 1
// baseline (675.343 us; speedup 1.0000x reference)
//
#include <hip/hip_runtime.h>
#include <math.h>

#define NLVL 16
#define MAXP (1u << 19)

struct LP {
    float        scale[NLVL];
    unsigned int res[NLVL];
    unsigned int hsize[NLVL];
    unsigned int offset[NLVL];
    unsigned int hashed[NLVL];
};

__global__ __launch_bounds__(256) void grid_enc_kernel(
    const float* __restrict__ in, const float* __restrict__ emb,
    float* __restrict__ out, int n, LP lp)
{
    int i = blockIdx.x * blockDim.x + threadIdx.x;
    if (i >= n) return;

    const float x = (in[3 * i + 0] + 1.0f) * 0.5f;
    const float y = (in[3 * i + 1] + 1.0f) * 0.5f;
    const float z = (in[3 * i + 2] + 1.0f) * 0.5f;

    float fout[2 * NLVL];

    #pragma unroll
    for (int l = 0; l < NLVL; ++l) {
        const float s  = lp.scale[l];
        const float px = x * s, py = y * s, pz = z * s;
        const float gx = floorf(px), gy = floorf(py), gz = floorf(pz);
        const float wx = px - gx, wy = py - gy, wz = pz - gz;
        const unsigned int bx = (unsigned int)(int)gx;
        const unsigned int by = (unsigned int)(int)gy;
        const unsigned int bz = (unsigned int)(int)gz;
        const unsigned int r   = lp.res[l];
        const unsigned int hs  = lp.hsize[l];
        const unsigned int off = lp.offset[l];
        const bool hashed = (lp.hashed[l] != 0u);

        float a0 = 0.0f, a1 = 0.0f;
        #pragma unroll
        for (int c = 0; c < 8; ++c) {
            const unsigned int dx = c & 1u, dy = (c >> 1) & 1u, dz = (c >> 2) & 1u;
            const unsigned int ix = bx + dx, iy = by + dy, iz = bz + dz;
            unsigned int idx;
            if (hashed) {
                // tcnn fast_hash: primes {1, 2654435761, 805459861}, uint32 wrap; hsize = 2^19
                idx = (ix ^ (iy * 2654435761u) ^ (iz * 805459861u)) & (hs - 1u);
            } else {
                // dense linear index; idx < 2*hs provably, so one conditional
                // subtract == reference's `% hsize` (covers x==1.0 edge at l=0)
                idx = ix + iy * r + iz * r * r;
                if (idx >= hs) idx -= hs;
            }
            const float2 f = *(const float2*)(emb + (size_t)(off + idx) * 2u);
            const float w = (dx ? wx : 1.0f - wx) *
                            (dy ? wy : 1.0f - wy) *
                            (dz ? wz : 1.0f - wz);
            a0 = fmaf(w, f.x, a0);
            a1 = fmaf(w, f.y, a1);
        }
        fout[2 * l + 0] = a0;
        fout[2 * l + 1] = a1;
    }

    float4* o4 = (float4*)(out + (size_t)i * 32);
    #pragma unroll
    for (int j = 0; j < 8; ++j)
        o4[j] = make_float4(fout[4 * j + 0], fout[4 * j + 1],
                            fout[4 * j + 2], fout[4 * j + 3]);
}

extern "C" void kernel_launch(void* const* d_in, const int* in_sizes, int n_in,
                              void* d_out, int out_size, void* d_ws, size_t ws_size,
                              hipStream_t stream)
{
    const float* in  = (const float*)d_in[0];
    const float* emb = (const float*)d_in[1];
    float* out = (float*)d_out;
    const int n = in_sizes[0] / 3;

    // Per-level params, computed in f64 exactly as the Python reference:
    // scale = 2^(l*log2(1.3819))*16 - 1; res = ceil(scale)+1;
    // pil = round8(min(2^19, res^3)); dense iff res^3 <= 2^19.
    LP lp;
    unsigned int offset = 0;
    const double log2s = log2(1.3819);
    for (int l = 0; l < NLVL; ++l) {
        const double scale = pow(2.0, (double)l * log2s) * 16.0 - 1.0;
        const int res = (int)ceil(scale) + 1;
        const long long r3 = (long long)res * res * res;
        const bool dense = (r3 <= (long long)MAXP);
        long long pil = dense ? r3 : (long long)MAXP;
        pil = (pil + 7) / 8 * 8;
        lp.scale[l]  = (float)scale;
        lp.res[l]    = (unsigned int)res;
        lp.hsize[l]  = (unsigned int)pil;
        lp.offset[l] = offset;
        lp.hashed[l] = dense ? 0u : 1u;
        offset += (unsigned int)pil;
    }

    const int block = 256;
    const int grid = (n + block - 1) / block;
    grid_enc_kernel<<<grid, block, 0, stream>>>(in, emb, out, n, lp);
}